// Round 1
// baseline (250.144 us; speedup 1.0000x reference)
//
#include <hip/hip_runtime.h>
#include <hip/hip_bf16.h>

// DT loss: trilinear lookup of 1M points into a 704x704x64 fp32 distance grid,
// outputs [mean, dist[N]]. Memory/gather bound; grid (127 MB) fits in the
// 256 MB Infinity Cache so gathers should be L3-served.

#define GH 704
#define GW 704
#define GD 64

__global__ __launch_bounds__(256) void dt_loss_kernel(
    const float* __restrict__ pc1,
    const float* __restrict__ flow,
    const float* __restrict__ grid,
    const float* __restrict__ grid_min,
    const int* __restrict__ grid_factor,
    float* __restrict__ out,   // out[0] = mean (pre-zeroed), out[1..N] = dist
    int N)
{
    const int i = blockIdx.x * blockDim.x + threadIdx.x;

    float val = 0.0f;
    if (i < N) {
        const float gf = (float)(*grid_factor);
        const float gmx = grid_min[0];
        const float gmy = grid_min[1];
        const float gmz = grid_min[2];

        const float px = pc1[3 * i + 0] + flow[3 * i + 0];
        const float py = pc1[3 * i + 1] + flow[3 * i + 1];
        const float pz = pc1[3 * i + 2] + flow[3 * i + 2];

        float sx = (px - gmx) * gf;
        float sy = (py - gmy) * gf;
        float sz = (pz - gmz) * gf;
        sx = fminf(fmaxf(sx, 0.0f), (float)(GH - 1));
        sy = fminf(fmaxf(sy, 0.0f), (float)(GW - 1));
        sz = fminf(fmaxf(sz, 0.0f), (float)(GD - 1));

        const int x0 = (int)floorf(sx);
        const int y0 = (int)floorf(sy);
        const int z0 = (int)floorf(sz);
        const int x1 = min(x0 + 1, GH - 1);
        const int y1 = min(y0 + 1, GW - 1);
        const int z1 = min(z0 + 1, GD - 1);

        const float wx = sx - (float)x0;
        const float wy = sy - (float)y0;
        const float wz = sz - (float)z0;

        const float* p00 = grid + ((size_t)x0 * GW + (size_t)y0) * GD;
        const float* p01 = grid + ((size_t)x0 * GW + (size_t)y1) * GD;
        const float* p10 = grid + ((size_t)x1 * GW + (size_t)y0) * GD;
        const float* p11 = grid + ((size_t)x1 * GW + (size_t)y1) * GD;

        const float c000 = p00[z0], c001 = p00[z1];
        const float c010 = p01[z0], c011 = p01[z1];
        const float c100 = p10[z0], c101 = p10[z1];
        const float c110 = p11[z0], c111 = p11[z1];

        const float c00 = c000 * (1.0f - wz) + c001 * wz;
        const float c01 = c010 * (1.0f - wz) + c011 * wz;
        const float c10 = c100 * (1.0f - wz) + c101 * wz;
        const float c11 = c110 * (1.0f - wz) + c111 * wz;

        const float c0 = c00 * (1.0f - wy) + c01 * wy;
        const float c1 = c10 * (1.0f - wy) + c11 * wy;

        val = c0 * (1.0f - wx) + c1 * wx;
        out[1 + i] = val;
    }

    // Block reduction for the mean: wave64 shuffle -> LDS -> one atomic/block.
    float s = val;
    #pragma unroll
    for (int off = 32; off > 0; off >>= 1)
        s += __shfl_down(s, off, 64);

    __shared__ float wsum[4];  // 256 threads / 64 lanes
    const int lane = threadIdx.x & 63;
    const int wid  = threadIdx.x >> 6;
    if (lane == 0) wsum[wid] = s;
    __syncthreads();
    if (threadIdx.x == 0) {
        const float part = wsum[0] + wsum[1] + wsum[2] + wsum[3];
        atomicAdd(out, part * (1.0f / (float)N));
    }
}

extern "C" void kernel_launch(void* const* d_in, const int* in_sizes, int n_in,
                              void* d_out, int out_size, void* d_ws, size_t ws_size,
                              hipStream_t stream) {
    const float* pc1        = (const float*)d_in[0];
    const float* flow       = (const float*)d_in[1];
    const float* grid       = (const float*)d_in[2];
    const float* grid_min   = (const float*)d_in[3];
    const int*   grid_factor= (const int*)d_in[4];
    float* out = (float*)d_out;

    const int N = in_sizes[0] / 3;  // pc1 is [1, N, 3]

    // out[0] accumulates the mean via atomics; harness poisons d_out each call.
    hipMemsetAsync(d_out, 0, sizeof(float), stream);

    const int block = 256;
    const int grid_sz = (N + block - 1) / block;
    dt_loss_kernel<<<grid_sz, block, 0, stream>>>(
        pc1, flow, grid, grid_min, grid_factor, out, N);
}

// Round 2
// 246.646 us; speedup vs baseline: 1.0142x; 1.0142x over previous
//
#include <hip/hip_runtime.h>
#include <hip/hip_bf16.h>

// DT loss: trilinear lookup of 1M points into a 704x704x64 fp32 distance grid,
// outputs [mean, dist[N]].
// R1: 96us kernel, FETCH=265MB (4 lines/point, L2 ~3% hit), VALUBusy 3% ->
// latency/MLP bound. R2: 4 points/thread, phase-split so all 16 gather lines
// per lane are outstanding at once (4x per-wave MLP).

#define GH 704
#define GW 704
#define GD 64
#define PTS 4

__global__ __launch_bounds__(256, 4) void dt_loss_kernel(
    const float* __restrict__ pc1,
    const float* __restrict__ flow,
    const float* __restrict__ grid,
    const float* __restrict__ grid_min,
    const int* __restrict__ grid_factor,
    float* __restrict__ out,   // out[0] = mean (pre-zeroed), out[1..N] = dist
    int N)
{
    const int T = gridDim.x * blockDim.x;       // total threads
    const int i0 = blockIdx.x * blockDim.x + threadIdx.x;

    const float gf = (float)(*grid_factor);
    const float gmx = grid_min[0];
    const float gmy = grid_min[1];
    const float gmz = grid_min[2];

    // ---- Phase 1: load all PTS points' coords (coalesced, independent) ----
    float px[PTS], py[PTS], pz[PTS];
    bool  act[PTS];
    #pragma unroll
    for (int j = 0; j < PTS; ++j) {
        const int i = i0 + j * T;
        act[j] = (i < N);
        const int ii = act[j] ? i : 0;
        px[j] = pc1[3 * ii + 0] + flow[3 * ii + 0];
        py[j] = pc1[3 * ii + 1] + flow[3 * ii + 1];
        pz[j] = pc1[3 * ii + 2] + flow[3 * ii + 2];
    }

    // ---- Phase 2: addresses + issue all corner gathers (32 loads in flight) ----
    float wx[PTS], wy[PTS], wz[PTS];
    float c000[PTS], c001[PTS], c010[PTS], c011[PTS];
    float c100[PTS], c101[PTS], c110[PTS], c111[PTS];
    #pragma unroll
    for (int j = 0; j < PTS; ++j) {
        float sx = (px[j] - gmx) * gf;
        float sy = (py[j] - gmy) * gf;
        float sz = (pz[j] - gmz) * gf;
        sx = fminf(fmaxf(sx, 0.0f), (float)(GH - 1));
        sy = fminf(fmaxf(sy, 0.0f), (float)(GW - 1));
        sz = fminf(fmaxf(sz, 0.0f), (float)(GD - 1));

        const int x0 = (int)sx;               // sx >= 0, floor == trunc
        const int y0 = (int)sy;
        const int z0 = (int)sz;
        const int x1 = min(x0 + 1, GH - 1);
        const int y1 = min(y0 + 1, GW - 1);
        const int z1 = min(z0 + 1, GD - 1);

        wx[j] = sx - (float)x0;
        wy[j] = sy - (float)y0;
        wz[j] = sz - (float)z0;

        const float* p00 = grid + ((size_t)x0 * GW + (size_t)y0) * GD;
        const float* p01 = grid + ((size_t)x0 * GW + (size_t)y1) * GD;
        const float* p10 = grid + ((size_t)x1 * GW + (size_t)y0) * GD;
        const float* p11 = grid + ((size_t)x1 * GW + (size_t)y1) * GD;

        c000[j] = p00[z0]; c001[j] = p00[z1];
        c010[j] = p01[z0]; c011[j] = p01[z1];
        c100[j] = p10[z0]; c101[j] = p10[z1];
        c110[j] = p11[z0]; c111[j] = p11[z1];
    }

    // ---- Phase 3: lerp + store + accumulate ----
    float acc = 0.0f;
    #pragma unroll
    for (int j = 0; j < PTS; ++j) {
        const float c00 = c000[j] * (1.0f - wz[j]) + c001[j] * wz[j];
        const float c01 = c010[j] * (1.0f - wz[j]) + c011[j] * wz[j];
        const float c10 = c100[j] * (1.0f - wz[j]) + c101[j] * wz[j];
        const float c11 = c110[j] * (1.0f - wz[j]) + c111[j] * wz[j];
        const float c0 = c00 * (1.0f - wy[j]) + c01 * wy[j];
        const float c1 = c10 * (1.0f - wy[j]) + c11 * wy[j];
        const float v  = c0 * (1.0f - wx[j]) + c1 * wx[j];
        if (act[j]) {
            out[1 + i0 + j * T] = v;
            acc += v;
        }
    }

    // ---- Mean: wave64 shuffle -> LDS -> one atomic/block ----
    float s = acc;
    #pragma unroll
    for (int off = 32; off > 0; off >>= 1)
        s += __shfl_down(s, off, 64);

    __shared__ float wsum[4];  // 256 threads / 64 lanes
    const int lane = threadIdx.x & 63;
    const int wid  = threadIdx.x >> 6;
    if (lane == 0) wsum[wid] = s;
    __syncthreads();
    if (threadIdx.x == 0) {
        const float part = wsum[0] + wsum[1] + wsum[2] + wsum[3];
        atomicAdd(out, part * (1.0f / (float)N));
    }
}

extern "C" void kernel_launch(void* const* d_in, const int* in_sizes, int n_in,
                              void* d_out, int out_size, void* d_ws, size_t ws_size,
                              hipStream_t stream) {
    const float* pc1        = (const float*)d_in[0];
    const float* flow       = (const float*)d_in[1];
    const float* grid       = (const float*)d_in[2];
    const float* grid_min   = (const float*)d_in[3];
    const int*   grid_factor= (const int*)d_in[4];
    float* out = (float*)d_out;

    const int N = in_sizes[0] / 3;  // pc1 is [1, N, 3]

    // out[0] accumulates the mean via atomics; harness poisons d_out each call.
    hipMemsetAsync(d_out, 0, sizeof(float), stream);

    const int block = 256;
    const int threads_needed = (N + PTS - 1) / PTS;
    const int grid_sz = (threads_needed + block - 1) / block;
    dt_loss_kernel<<<grid_sz, block, 0, stream>>>(
        pc1, flow, grid, grid_min, grid_factor, out, N);
}